// Round 3
// baseline (113.049 us; speedup 1.0000x reference)
//
#include <hip/hip_runtime.h>

#define THREADS 256
#define QPB 2
#define KNN 32
#define CAP 512
#define MAXRETRY 34

constexpr int Bc = 4, Nc = 8192, Sc = 2048, Cch = 64;

__device__ __forceinline__ unsigned dist2bits(float qx, float qy, float qz,
                                              float x, float y, float z) {
  // bit-exact vs numpy f32: no FMA contraction, fixed add order
  const float dx = __fsub_rn(qx, x);
  const float dy = __fsub_rn(qy, y);
  const float dz = __fsub_rn(qz, z);
  return __float_as_uint(__fadd_rn(
      __fadd_rn(__fmul_rn(dx, dx), __fmul_rn(dy, dy)), __fmul_rn(dz, dz)));
}

__global__ __launch_bounds__(THREADS) void neighbor_group_kernel(
    const float* __restrict__ xyz,      // (B, N, 3)
    const float* __restrict__ new_xyz,  // (B, S, 3)
    const float* __restrict__ feat,     // (B, N, C)
    float* __restrict__ out)
{
  __shared__ unsigned candDb[QPB][CAP];
  __shared__ unsigned candIdx[QPB][CAP];
  __shared__ unsigned winIdx[QPB][KNN];
  __shared__ unsigned winDb[QPB][KNN];
  __shared__ unsigned ccnt[QPB];
  __shared__ unsigned wavePiv[QPB][4];

  const int tid  = threadIdx.x;
  const int lane = tid & 63;
  const int wid  = tid >> 6;
  const int q0   = blockIdx.x * QPB;
  const int b    = q0 >> 11;           // / S (S = 2048)

  const float qx0 = new_xyz[q0 * 3 + 0];
  const float qy0 = new_xyz[q0 * 3 + 1];
  const float qz0 = new_xyz[q0 * 3 + 2];
  const float qx1 = new_xyz[q0 * 3 + 3];
  const float qy1 = new_xyz[q0 * 3 + 4];
  const float qz1 = new_xyz[q0 * 3 + 5];

  const float4* __restrict__ xb4 = (const float4*)(xyz + (size_t)b * Nc * 3);

  // ---- pass 1: per-thread min dist^2 bits per query (no key storage) ----
  unsigned lmin0 = 0xFFFFFFFFu, lmin1 = 0xFFFFFFFFu;
#pragma unroll
  for (int j2 = 0; j2 < 8; ++j2) {
    const int g = tid + j2 * THREADS;
    const float4 f0 = xb4[3 * g + 0];
    const float4 f1 = xb4[3 * g + 1];
    const float4 f2 = xb4[3 * g + 2];
    const float px[4] = {f0.x, f0.w, f1.z, f2.y};
    const float py[4] = {f0.y, f1.x, f1.w, f2.z};
    const float pz[4] = {f0.z, f1.y, f2.x, f2.w};
#pragma unroll
    for (int k = 0; k < 4; ++k) {
      const unsigned k0 = dist2bits(qx0, qy0, qz0, px[k], py[k], pz[k]);
      const unsigned k1 = dist2bits(qx1, qy1, qz1, px[k], py[k], pz[k]);
      lmin0 = min(lmin0, k0);
      lmin1 = min(lmin1, k1);
    }
  }

  // ---- per-wave 8th-smallest of the 64 mins via bitwise ballot select ----
  // builds largest P with count(mins < P) < 8; pivot = P+1 -> count >= 8/wave
  unsigned P0 = 0u, P1 = 0u;
#pragma unroll
  for (int bb = 30; bb >= 0; --bb) {
    const unsigned t0 = P0 | (1u << bb);
    const unsigned t1 = P1 | (1u << bb);
    const unsigned long long m0 = __ballot(lmin0 < t0);
    const unsigned long long m1 = __ballot(lmin1 < t1);
    if (__popcll(m0) < 8) P0 = t0;
    if (__popcll(m1) < 8) P1 = t1;
  }
  if (lane == 0) { wavePiv[0][wid] = P0 + 1u; wavePiv[1][wid] = P1 + 1u; }
  __syncthreads();
  // max over waves: >= 8 elements below per wave -> >= 32 block-wide
  unsigned piv0 = max(max(wavePiv[0][0], wavePiv[0][1]),
                      max(wavePiv[0][2], wavePiv[0][3]));
  unsigned piv1 = max(max(wavePiv[1][0], wavePiv[1][1]),
                      max(wavePiv[1][2], wavePiv[1][3]));

  // ---- pass 2: compaction (recompute dist^2); retry bisection if overflow --
  unsigned lo0 = 0u, hi0 = 0xFFFFFFFFu, lo1 = 0u, hi1 = 0xFFFFFFFFu;
  bool forced0 = false, forced1 = false;
  unsigned C0 = 0, C1 = 0;
  for (int it = 0; it < MAXRETRY; ++it) {
    __syncthreads();
    if (tid < QPB) ccnt[tid] = 0u;
    __syncthreads();
#pragma unroll
    for (int j2 = 0; j2 < 8; ++j2) {
      const int g = tid + j2 * THREADS;
      const float4 f0 = xb4[3 * g + 0];
      const float4 f1 = xb4[3 * g + 1];
      const float4 f2 = xb4[3 * g + 2];
      const float px[4] = {f0.x, f0.w, f1.z, f2.y};
      const float py[4] = {f0.y, f1.x, f1.w, f2.z};
      const float pz[4] = {f0.z, f1.y, f2.x, f2.w};
#pragma unroll
      for (int k = 0; k < 4; ++k) {
        const unsigned pidx = (unsigned)(4 * g + k);
        const unsigned k0 = dist2bits(qx0, qy0, qz0, px[k], py[k], pz[k]);
        if (k0 < piv0) {
          const unsigned pos = atomicAdd(&ccnt[0], 1u);
          if (pos < CAP) { candDb[0][pos] = k0; candIdx[0][pos] = pidx; }
        }
        const unsigned k1 = dist2bits(qx1, qy1, qz1, px[k], py[k], pz[k]);
        if (k1 < piv1) {
          const unsigned pos = atomicAdd(&ccnt[1], 1u);
          if (pos < CAP) { candDb[1][pos] = k1; candIdx[1][pos] = pidx; }
        }
      }
    }
    __syncthreads();
    const unsigned c0 = ccnt[0], c1 = ccnt[1];
    C0 = min(c0, (unsigned)CAP);
    C1 = min(c1, (unsigned)CAP);
    const bool ok0 = forced0 || (c0 >= KNN && c0 <= CAP);
    const bool ok1 = forced1 || (c1 >= KNN && c1 <= CAP);
    if (ok0 && ok1) break;
    if (!ok0) {
      if (c0 < KNN) lo0 = piv0; else hi0 = piv0;
      if (hi0 - lo0 <= 1u) { piv0 = hi0; forced0 = true; }
      else piv0 = lo0 + ((hi0 - lo0) >> 1);
    }
    if (!ok1) {
      if (c1 < KNN) lo1 = piv1; else hi1 = piv1;
      if (hi1 - lo1 <= 1u) { piv1 = hi1; forced1 = true; }
      else piv1 = lo1 + ((hi1 - lo1) >> 1);
    }
  }

  // ---- sqrt only the candidates (numpy ranks/outputs use sqrt f32 bits) ----
  for (unsigned t = tid; t < C0; t += THREADS)
    candDb[0][t] = __float_as_uint(__fsqrt_rn(__uint_as_float(candDb[0][t])));
  for (unsigned t = tid; t < C1; t += THREADS)
    candDb[1][t] = __float_as_uint(__fsqrt_rn(__uint_as_float(candDb[1][t])));
  __syncthreads();

  // ---- exact rank by (sqrt bits, idx) lexicographic; ranks unique ----
#pragma unroll
  for (int qi = 0; qi < QPB; ++qi) {
    const unsigned Cc = (qi == 0) ? C0 : C1;
    for (unsigned t = tid; t < Cc; t += THREADS) {
      const unsigned mdb = candDb[qi][t];
      const unsigned mix = candIdx[qi][t];
      unsigned rank = 0;
      for (unsigned o = 0; o < Cc; ++o) {
        const unsigned odb = candDb[qi][o];
        const unsigned oix = candIdx[qi][o];
        rank += (odb < mdb || (odb == mdb && oix < mix)) ? 1u : 0u;
      }
      if (rank < KNN) { winIdx[qi][rank] = mix; winDb[qi][rank] = mdb; }
    }
  }
  __syncthreads();

  // ---- outputs (flat concat: nxyz | idxs | nfeat | values), all f32 ----
  float* out_nx = out;                                   // B*S*K*3
  float* out_id = out + (size_t)Bc * Sc * KNN * 3;       // B*S*K
  float* out_nf = out_id + (size_t)Bc * Sc * KNN;        // B*S*K*C
  float* out_sv = out_nf + (size_t)Bc * Sc * KNN * Cch;  // B*S*K

  const float* xb = xyz + (size_t)b * Nc * 3;
  const float4* fb4 = (const float4*)(feat + (size_t)b * Nc * Cch);

#pragma unroll
  for (int qi = 0; qi < QPB; ++qi) {
    const int q = q0 + qi;
    if (tid < KNN) {
      out_id[(size_t)q * KNN + tid] = (float)winIdx[qi][tid];
      out_sv[(size_t)q * KNN + tid] = __uint_as_float(winDb[qi][tid]);
    }
    if (tid < KNN * 3) {
      const int w = tid / 3, c3 = tid % 3;
      out_nx[((size_t)q * KNN + w) * 3 + c3] =
          xb[(size_t)winIdx[qi][w] * 3 + c3];
    }
    float4* onf4 = (float4*)(out_nf + (size_t)q * KNN * Cch);
#pragma unroll
    for (int r = 0; r < 2; ++r) {
      const int flat = tid + r * THREADS;   // 0..511
      const int w = flat >> 4;              // winner 0..31
      const int c4 = flat & 15;
      onf4[w * 16 + c4] = fb4[(size_t)winIdx[qi][w] * 16 + c4];
    }
  }
}

extern "C" void kernel_launch(void* const* d_in, const int* in_sizes, int n_in,
                              void* d_out, int out_size, void* d_ws, size_t ws_size,
                              hipStream_t stream) {
  const float* xyz     = (const float*)d_in[0];
  const float* new_xyz = (const float*)d_in[1];
  const float* feat    = (const float*)d_in[2];
  float* out = (float*)d_out;

  const int grid = (Bc * Sc) / QPB;  // 4096 blocks, 2 queries each
  neighbor_group_kernel<<<grid, THREADS, 0, stream>>>(xyz, new_xyz, feat, out);
}